// Round 1
// baseline (194.935 us; speedup 1.0000x reference)
//
#include <hip/hip_runtime.h>
#include <math.h>

#define TEMP_INV (1.0f / 0.07f)
#define WEIGHT 0.5f
#define EPS 1e-8f
#define BB 64
#define TT 512
#define DD 512

__device__ inline float wave_sum(float v) {
    for (int o = 32; o >= 1; o >>= 1) v += __shfl_xor(v, o, 64);
    return v;
}
__device__ inline int wave_max_i(int v) {
    for (int o = 32; o >= 1; o >>= 1) v = max(v, __shfl_xor(v, o, 64));
    return v;
}
__device__ inline int wave_min_i(int v) {
    for (int o = 32; o >= 1; o >>= 1) v = min(v, __shfl_xor(v, o, 64));
    return v;
}

// One block (256 threads) per batch element b:
//  - argmax(mask[b,:]) with first-occurrence semantics
//  - normalized anchors a_anchor[b,:], v_anchor[b,:]
//  - pos[b] = dot(v_anchor_n, a_anchor_n)/TEMP
//  - zero the neg accumulators (ws is poisoned each call)
__global__ __launch_bounds__(256) void prep_kernel(
    const float* __restrict__ video, const float* __restrict__ audio,
    const int* __restrict__ mask,
    float* __restrict__ a_anchor, float* __restrict__ v_anchor,
    float* __restrict__ pos, float* __restrict__ neg, int* __restrict__ idx_out)
{
    const int b = blockIdx.x;
    const int tid = threadIdx.x;
    const int wid = tid >> 6, lane = tid & 63;
    __shared__ int sh_i[4];
    __shared__ float sh_f[4][3];
    __shared__ int s_idx;
    __shared__ float s_inva, s_invv;

    // ---- argmax (first max) over mask[b, 0..T) ----
    int m0 = mask[b * TT + tid];
    int m1 = mask[b * TT + tid + 256];
    int vmax = wave_max_i(max(m0, m1));
    if (lane == 0) sh_i[wid] = vmax;
    __syncthreads();
    if (tid == 0) {
        int r = sh_i[0];
        for (int i = 1; i < 4; i++) r = max(r, sh_i[i]);
        sh_i[0] = r;
    }
    __syncthreads();
    vmax = sh_i[0];
    __syncthreads();
    int cand = (m0 == vmax) ? tid : 0x7fffffff;
    int cand1 = (m1 == vmax) ? (tid + 256) : 0x7fffffff;
    cand = min(cand, cand1);
    cand = wave_min_i(cand);
    if (lane == 0) sh_i[wid] = cand;
    __syncthreads();
    if (tid == 0) {
        int r = sh_i[0];
        for (int i = 1; i < 4; i++) r = min(r, sh_i[i]);
        s_idx = r;
    }
    __syncthreads();
    const int idx = s_idx;

    // ---- anchor rows: sumsq(audio), sumsq(video), dot(audio,video) ----
    const float* arow = audio + ((size_t)(b * TT + idx)) * DD;
    const float* vrow = video + ((size_t)(b * TT + idx)) * DD;
    float a0 = arow[tid], a1 = arow[tid + 256];
    float v0 = vrow[tid], v1 = vrow[tid + 256];
    float ssa = a0 * a0 + a1 * a1;
    float ssv = v0 * v0 + v1 * v1;
    float dav = a0 * v0 + a1 * v1;
    ssa = wave_sum(ssa);
    ssv = wave_sum(ssv);
    dav = wave_sum(dav);
    if (lane == 0) { sh_f[wid][0] = ssa; sh_f[wid][1] = ssv; sh_f[wid][2] = dav; }
    __syncthreads();
    if (tid == 0) {
        float ra = 0.f, rv = 0.f, rd = 0.f;
        for (int i = 0; i < 4; i++) { ra += sh_f[i][0]; rv += sh_f[i][1]; rd += sh_f[i][2]; }
        float inva = 1.0f / fmaxf(sqrtf(ra), EPS);
        float invv = 1.0f / fmaxf(sqrtf(rv), EPS);
        s_inva = inva; s_invv = invv;
        pos[b] = rd * inva * invv * TEMP_INV;
        neg[b] = 0.0f;
        neg[BB + b] = 0.0f;
        idx_out[b] = idx;
    }
    __syncthreads();
    const float inva = s_inva, invv = s_invv;
    a_anchor[b * DD + tid] = a0 * inva;
    a_anchor[b * DD + tid + 256] = a1 * inva;
    v_anchor[b * DD + tid] = v0 * invv;
    v_anchor[b * DD + tid + 256] = v1 * invv;
}

// grid (T/4, B, 2); one 64-lane wave per (b,t,dir) row.
// dir==0: sims_a2v = dot(vn[b,t], a_anchor)/TEMP ; dir==1: sims_v2a.
__global__ __launch_bounds__(256) void sims_kernel(
    const float* __restrict__ video, const float* __restrict__ audio,
    const float* __restrict__ a_anchor, const float* __restrict__ v_anchor,
    const int* __restrict__ idx_arr, float* __restrict__ neg)
{
    const int b = blockIdx.y;
    const int dir = blockIdx.z;
    const int wid = threadIdx.x >> 6, lane = threadIdx.x & 63;
    const int t = blockIdx.x * 4 + wid;

    const float* row = (dir == 0 ? video : audio) + ((size_t)(b * TT + t)) * DD;
    const float* anc = (dir == 0 ? a_anchor : v_anchor) + b * DD;

    float4 r0 = *(const float4*)(row + lane * 4);
    float4 r1 = *(const float4*)(row + 256 + lane * 4);
    float4 c0 = *(const float4*)(anc + lane * 4);
    float4 c1 = *(const float4*)(anc + 256 + lane * 4);

    float dot = r0.x * c0.x + r0.y * c0.y + r0.z * c0.z + r0.w * c0.w
              + r1.x * c1.x + r1.y * c1.y + r1.z * c1.z + r1.w * c1.w;
    float nrm = r0.x * r0.x + r0.y * r0.y + r0.z * r0.z + r0.w * r0.w
              + r1.x * r1.x + r1.y * r1.y + r1.z * r1.z + r1.w * r1.w;
    for (int o = 32; o >= 1; o >>= 1) {
        dot += __shfl_xor(dot, o, 64);
        nrm += __shfl_xor(nrm, o, 64);
    }

    __shared__ float se[4];
    if (lane == 0) {
        float sim = dot / fmaxf(sqrtf(nrm), EPS) * TEMP_INV;
        se[wid] = (t == idx_arr[b]) ? 0.0f : expf(sim);
    }
    __syncthreads();
    if (threadIdx.x == 0) {
        atomicAdd(&neg[dir * BB + b], se[0] + se[1] + se[2] + se[3]);
    }
}

__global__ void finalize_kernel(const float* __restrict__ pos,
                                const float* __restrict__ neg,
                                float* __restrict__ out)
{
    const int b = threadIdx.x;  // 64 threads, one wave
    float term = WEIGHT * (logf(neg[b]) + logf(neg[BB + b])) - pos[b];
    term = wave_sum(term);
    if (b == 0) out[0] = term / (float)BB;
}

extern "C" void kernel_launch(void* const* d_in, const int* in_sizes, int n_in,
                              void* d_out, int out_size, void* d_ws, size_t ws_size,
                              hipStream_t stream)
{
    const float* video = (const float*)d_in[0];
    const float* audio = (const float*)d_in[1];
    const int* mask = (const int*)d_in[2];

    float* ws = (float*)d_ws;
    float* a_anchor = ws;                 // B*D
    float* v_anchor = ws + BB * DD;       // B*D
    float* pos = ws + 2 * BB * DD;        // B
    float* neg = pos + BB;                // 2*B
    int* idx = (int*)(neg + 2 * BB);      // B

    prep_kernel<<<BB, 256, 0, stream>>>(video, audio, mask, a_anchor, v_anchor, pos, neg, idx);
    dim3 grid(TT / 4, BB, 2);
    sims_kernel<<<grid, 256, 0, stream>>>(video, audio, a_anchor, v_anchor, idx, neg);
    finalize_kernel<<<1, 64, 0, stream>>>(pos, neg, (float*)d_out);
}

// Round 2
// 167.566 us; speedup vs baseline: 1.1633x; 1.1633x over previous
//
#include <hip/hip_runtime.h>
#include <math.h>

#define TEMP_INV (1.0f / 0.07f)
#define WEIGHT 0.5f
#define EPS 1e-8f
#define BB 64
#define TT 512
#define DD 512
#define RR 8   // rows per wave in sims_kernel

__device__ inline float wave_sum(float v) {
    for (int o = 32; o >= 1; o >>= 1) v += __shfl_xor(v, o, 64);
    return v;
}
__device__ inline int wave_max_i(int v) {
    for (int o = 32; o >= 1; o >>= 1) v = max(v, __shfl_xor(v, o, 64));
    return v;
}
__device__ inline int wave_min_i(int v) {
    for (int o = 32; o >= 1; o >>= 1) v = min(v, __shfl_xor(v, o, 64));
    return v;
}

// One block (256 threads) per batch element b:
//  - argmax(mask[b,:]) with first-occurrence semantics
//  - normalized anchors a_anchor[b,:], v_anchor[b,:]
//  - pos[b] = dot(v_anchor_n, a_anchor_n)/TEMP
//  - zero the neg accumulators (ws is poisoned each call)
__global__ __launch_bounds__(256) void prep_kernel(
    const float* __restrict__ video, const float* __restrict__ audio,
    const int* __restrict__ mask,
    float* __restrict__ a_anchor, float* __restrict__ v_anchor,
    float* __restrict__ pos, float* __restrict__ neg, int* __restrict__ idx_out)
{
    const int b = blockIdx.x;
    const int tid = threadIdx.x;
    const int wid = tid >> 6, lane = tid & 63;
    __shared__ int sh_i[4];
    __shared__ float sh_f[4][3];
    __shared__ int s_idx;
    __shared__ float s_inva, s_invv;

    // ---- argmax (first max) over mask[b, 0..T) ----
    int m0 = mask[b * TT + tid];
    int m1 = mask[b * TT + tid + 256];
    int vmax = wave_max_i(max(m0, m1));
    if (lane == 0) sh_i[wid] = vmax;
    __syncthreads();
    if (tid == 0) {
        int r = sh_i[0];
        for (int i = 1; i < 4; i++) r = max(r, sh_i[i]);
        sh_i[0] = r;
    }
    __syncthreads();
    vmax = sh_i[0];
    __syncthreads();
    int cand = (m0 == vmax) ? tid : 0x7fffffff;
    int cand1 = (m1 == vmax) ? (tid + 256) : 0x7fffffff;
    cand = min(cand, cand1);
    cand = wave_min_i(cand);
    if (lane == 0) sh_i[wid] = cand;
    __syncthreads();
    if (tid == 0) {
        int r = sh_i[0];
        for (int i = 1; i < 4; i++) r = min(r, sh_i[i]);
        s_idx = r;
    }
    __syncthreads();
    const int idx = s_idx;

    // ---- anchor rows: sumsq(audio), sumsq(video), dot(audio,video) ----
    const float* arow = audio + ((size_t)(b * TT + idx)) * DD;
    const float* vrow = video + ((size_t)(b * TT + idx)) * DD;
    float a0 = arow[tid], a1 = arow[tid + 256];
    float v0 = vrow[tid], v1 = vrow[tid + 256];
    float ssa = a0 * a0 + a1 * a1;
    float ssv = v0 * v0 + v1 * v1;
    float dav = a0 * v0 + a1 * v1;
    ssa = wave_sum(ssa);
    ssv = wave_sum(ssv);
    dav = wave_sum(dav);
    if (lane == 0) { sh_f[wid][0] = ssa; sh_f[wid][1] = ssv; sh_f[wid][2] = dav; }
    __syncthreads();
    if (tid == 0) {
        float ra = 0.f, rv = 0.f, rd = 0.f;
        for (int i = 0; i < 4; i++) { ra += sh_f[i][0]; rv += sh_f[i][1]; rd += sh_f[i][2]; }
        float inva = 1.0f / fmaxf(sqrtf(ra), EPS);
        float invv = 1.0f / fmaxf(sqrtf(rv), EPS);
        s_inva = inva; s_invv = invv;
        pos[b] = rd * inva * invv * TEMP_INV;
        neg[b] = 0.0f;
        neg[BB + b] = 0.0f;
        idx_out[b] = idx;
    }
    __syncthreads();
    const float inva = s_inva, invv = s_invv;
    a_anchor[b * DD + tid] = a0 * inva;
    a_anchor[b * DD + tid + 256] = a1 * inva;
    v_anchor[b * DD + tid] = v0 * invv;
    v_anchor[b * DD + tid + 256] = v1 * invv;
}

// grid (T/(4*RR), B, 2); one 64-lane wave per RR consecutive (b,t,dir) rows.
// dir==0: sims_a2v = dot(vn[b,t], a_anchor)/TEMP ; dir==1: sims_v2a.
// Per wave: 16 independent float4 loads up front (MLP), 16 independent
// accumulators, one batched 6-level butterfly (16 indep shfls per level),
// no __syncthreads, one atomicAdd per wave.
__global__ __launch_bounds__(256) void sims_kernel(
    const float* __restrict__ video, const float* __restrict__ audio,
    const float* __restrict__ a_anchor, const float* __restrict__ v_anchor,
    const int* __restrict__ idx_arr, float* __restrict__ neg)
{
    const int b = blockIdx.y;
    const int dir = blockIdx.z;
    const int wid = threadIdx.x >> 6, lane = threadIdx.x & 63;
    const int t0 = blockIdx.x * (4 * RR) + wid * RR;

    const float* base = (dir == 0 ? video : audio) + (size_t)b * TT * DD;
    const float* anc = (dir == 0 ? a_anchor : v_anchor) + b * DD;

    float4 c0 = *(const float4*)(anc + lane * 4);
    float4 c1 = *(const float4*)(anc + 256 + lane * 4);

    float4 r0[RR], r1[RR];
#pragma unroll
    for (int r = 0; r < RR; r++) {
        const float* row = base + (size_t)(t0 + r) * DD;
        r0[r] = *(const float4*)(row + lane * 4);
        r1[r] = *(const float4*)(row + 256 + lane * 4);
    }

    float dot[RR], nrm[RR];
#pragma unroll
    for (int r = 0; r < RR; r++) {
        dot[r] = r0[r].x * c0.x + r0[r].y * c0.y + r0[r].z * c0.z + r0[r].w * c0.w
               + r1[r].x * c1.x + r1[r].y * c1.y + r1[r].z * c1.z + r1[r].w * c1.w;
        nrm[r] = r0[r].x * r0[r].x + r0[r].y * r0[r].y + r0[r].z * r0[r].z + r0[r].w * r0[r].w
               + r1[r].x * r1[r].x + r1[r].y * r1[r].y + r1[r].z * r1[r].z + r1[r].w * r1[r].w;
    }

    // batched butterfly: 6 levels, 2*RR independent shfl-adds per level
#pragma unroll
    for (int o = 32; o >= 1; o >>= 1) {
#pragma unroll
        for (int r = 0; r < RR; r++) {
            dot[r] += __shfl_xor(dot[r], o, 64);
            nrm[r] += __shfl_xor(nrm[r], o, 64);
        }
    }

    if (lane == 0) {
        const int idx = idx_arr[b];
        float local = 0.0f;
#pragma unroll
        for (int r = 0; r < RR; r++) {
            const int t = t0 + r;
            float sim = dot[r] / fmaxf(sqrtf(nrm[r]), EPS) * TEMP_INV;
            local += (t == idx) ? 0.0f : expf(sim);
        }
        atomicAdd(&neg[dir * BB + b], local);
    }
}

__global__ void finalize_kernel(const float* __restrict__ pos,
                                const float* __restrict__ neg,
                                float* __restrict__ out)
{
    const int b = threadIdx.x;  // 64 threads, one wave
    float term = WEIGHT * (logf(neg[b]) + logf(neg[BB + b])) - pos[b];
    term = wave_sum(term);
    if (b == 0) out[0] = term / (float)BB;
}

extern "C" void kernel_launch(void* const* d_in, const int* in_sizes, int n_in,
                              void* d_out, int out_size, void* d_ws, size_t ws_size,
                              hipStream_t stream)
{
    const float* video = (const float*)d_in[0];
    const float* audio = (const float*)d_in[1];
    const int* mask = (const int*)d_in[2];

    float* ws = (float*)d_ws;
    float* a_anchor = ws;                 // B*D
    float* v_anchor = ws + BB * DD;       // B*D
    float* pos = ws + 2 * BB * DD;        // B
    float* neg = pos + BB;                // 2*B
    int* idx = (int*)(neg + 2 * BB);      // B

    prep_kernel<<<BB, 256, 0, stream>>>(video, audio, mask, a_anchor, v_anchor, pos, neg, idx);
    dim3 grid(TT / (4 * RR), BB, 2);
    sims_kernel<<<grid, 256, 0, stream>>>(video, audio, a_anchor, v_anchor, idx, neg);
    finalize_kernel<<<1, 64, 0, stream>>>(pos, neg, (float*)d_out);
}